// Round 7
// baseline (272.493 us; speedup 1.0000x reference)
//
#include <hip/hip_runtime.h>

namespace {
constexpr int B_ = 8, H_ = 16, CI_ = 16, O_ = 16, P_ = 14;
constexpr int P2_ = P_ * P_;    // 196
constexpr int K2CI_ = 144;
constexpr int NV_ = 2304;       // z per patch, layout [k][o]
constexpr float EPS_ = 1e-9f;
constexpr float LOG2PI_ = 1.8378770664093453f;

__device__ __forceinline__ float cnt1(int h) {
  int lo = (h - (P_ - 1)) > 0 ? (h - (P_ - 1)) : 0;
  int hi = h < 2 ? h : 2;
  return (float)(hi - lo + 1);
}

// wt[k][o][r][q] = w[k][o][q][r]
__global__ __launch_bounds__(256) void transpose_w(const float* __restrict__ w,
                                                   float* __restrict__ wt) {
  const int i = blockIdx.x * 256 + threadIdx.x;
  const int ko = i >> 4, q = (i >> 2) & 3, r = i & 3;
  wt[(ko << 4) + (r << 2) + q] = w[i];
}

// One BLOCK (576 thr, 9 waves) per patch; wave wv owns kk=wv (16 ci's).
// lane = o*4 + r ; lane covers dims d = p*4+r, p=0..3.
// MODE 0: rr uniform -> z. MODE 1: rr softmax -> z. MODE 2: rr softmax -> outputs.
template <int MODE>
__global__ __launch_bounds__(576) void caps_main(
    const float* __restrict__ pose, const float* __restrict__ act,
    const float* __restrict__ wt, const float* __restrict__ beta_a,
    const float* __restrict__ beta_v, const float* __restrict__ zin,
    const float* __restrict__ gmax, const float* __restrict__ gden,
    float* __restrict__ zout, float* __restrict__ out) {
  __shared__ float rr_s[(MODE == 0) ? K2CI_ : NV_];  // MODE0: rr0[k] ; else rr[k][o]
  __shared__ float part[9][576];                     // Welford partials [stat][wv*64+l]
  __shared__ float gm_s[(MODE == 0) ? 1 : K2CI_];
  __shared__ float ad_s[(MODE == 0) ? 1 : K2CI_];

  const int tid = threadIdx.x;
  const int wv = __builtin_amdgcn_readfirstlane(tid / 64);  // == kk, wave-uniform
  const int l = tid & 63;
  const int o = l >> 2, r = l & 3;
  const int pid = blockIdx.x;
  const int b = pid / P2_;
  const int p2 = pid - b * P2_;
  const int pi = p2 / P_;
  const int pj = p2 - pi * P_;
  const float inv_temp = (MODE == 0) ? 0.0005f : (MODE == 1) ? 0.000975f : 0.00142625f;

  // ---- prologue: stage rr (or gmax/act-den) into LDS ----
  if (MODE == 0) {
    if (tid < K2CI_) {
      const int ci = tid & 15, kk = tid >> 4;
      const int ki = (kk >= 6) ? 2 : (kk >= 3) ? 1 : 0, kj = kk - 3 * ki;
      const int cidx = ((b * H_ + pi + ki) * H_ + pj + kj) * CI_ + ci;
      rr_s[tid] = act[cidx] / (16.0f * cnt1(pi + ki) * cnt1(pj + kj));
    }
  } else {
    if (tid < K2CI_) {
      const int ci = tid & 15, kk = tid >> 4;
      const int ki = (kk >= 6) ? 2 : (kk >= 3) ? 1 : 0, kj = kk - 3 * ki;
      const int cidx = ((b * H_ + pi + ki) * H_ + pj + kj) * CI_ + ci;
      gm_s[tid] = gmax[cidx];
      ad_s[tid] = act[cidx] / (gden[cidx] + EPS_);
    }
    __syncthreads();
    // NV_/4 == 576: exactly one float4 per thread
    const float4 z4 = ((const float4*)(zin + (size_t)pid * NV_))[tid];
    const int k = tid >> 2;
    const float gmk = gm_s[k], adk = ad_s[k];
    float4 r4;
    r4.x = __expf(z4.x - gmk) * adk;
    r4.y = __expf(z4.y - gmk) * adk;
    r4.z = __expf(z4.z - gmk) * adk;
    r4.w = __expf(z4.w - gmk) * adk;
    ((float4*)rr_s)[tid] = r4;
  }
  __syncthreads();

  const float bvo = 16.0f * beta_v[o];
  const float bao = beta_a[o];

  // ---- wave-uniform bases (computed once; SALU) ----
  const int kk = wv;
  const int ki = (kk >= 6) ? 2 : (kk >= 3) ? 1 : 0, kj = kk - 3 * ki;
  const float* pb = pose + ((size_t)((b * H_ + pi + ki) * H_ + pj + kj) << 8);
  const float* wb = wt + ((size_t)(kk * 16) << 8) + (l << 2);

  // ---- pass 1: fused mean+var partials over this wave's 16 ci ----
  float vreg[16][4];
  float prr = 0.f;
  float pm0 = 0.f, pm1 = 0.f, pm2 = 0.f, pm3 = 0.f;
  float pv0 = 0.f, pv1 = 0.f, pv2 = 0.f, pv3 = 0.f;
#pragma unroll
  for (int ci = 0; ci < 16; ++ci) {
    const float4 w4 = *(const float4*)(wb + (ci << 8));
    const float4 Pa = *(const float4*)(pb + (ci << 4));
    const float4 Pb = *(const float4*)(pb + (ci << 4) + 4);
    const float4 Pc = *(const float4*)(pb + (ci << 4) + 8);
    const float4 Pd = *(const float4*)(pb + (ci << 4) + 12);
    const float v0 = Pa.x * w4.x + Pa.y * w4.y + Pa.z * w4.z + Pa.w * w4.w;
    const float v1 = Pb.x * w4.x + Pb.y * w4.y + Pb.z * w4.z + Pb.w * w4.w;
    const float v2 = Pc.x * w4.x + Pc.y * w4.y + Pc.z * w4.z + Pc.w * w4.w;
    const float v3 = Pd.x * w4.x + Pd.y * w4.y + Pd.z * w4.z + Pd.w * w4.w;
    const float rrk = (MODE == 0) ? rr_s[kk * 16 + ci] : rr_s[((kk * 16 + ci) << 4) + o];
    if (MODE != 2) {
      vreg[ci][0] = v0; vreg[ci][1] = v1; vreg[ci][2] = v2; vreg[ci][3] = v3;
    }
    prr += rrk;
    const float a0 = rrk * v0, a1 = rrk * v1, a2 = rrk * v2, a3 = rrk * v3;
    pm0 += a0; pm1 += a1; pm2 += a2; pm3 += a3;
    pv0 = fmaf(a0, v0, pv0); pv1 = fmaf(a1, v1, pv1);
    pv2 = fmaf(a2, v2, pv2); pv3 = fmaf(a3, v3, pv3);
  }
  // ---- combine partials across 9 waves via LDS (stride-1, conflict-free) ----
  part[0][tid] = prr;
  part[1][tid] = pm0; part[2][tid] = pm1; part[3][tid] = pm2; part[4][tid] = pm3;
  part[5][tid] = pv0; part[6][tid] = pv1; part[7][tid] = pv2; part[8][tid] = pv3;
  __syncthreads();
  float s[9];
#pragma unroll
  for (int j = 0; j < 9; ++j) {
    float acc = part[j][l];
#pragma unroll
    for (int wvi = 1; wvi < 9; ++wvi) acc += part[j][wvi * 64 + l];
    s[j] = acc;
  }
  const float rsum = s[0] + EPS_;
  const float irs = 1.0f / rsum;
  const float m0 = s[1] * irs, m1 = s[2] * irs, m2 = s[3] * irs, m3 = s[4] * irs;
  const float va0 = fmaxf(s[5] * irs - m0 * m0, 0.f) + EPS_;
  const float va1 = fmaxf(s[6] * irs - m1 * m1, 0.f) + EPS_;
  const float va2 = fmaxf(s[7] * irs - m2 * m2, 0.f) + EPS_;
  const float va3 = fmaxf(s[8] * irs - m3 * m3, 0.f) + EPS_;
  float slv = __logf(va0) + __logf(va1) + __logf(va2) + __logf(va3);
  slv += __shfl_xor(slv, 1);
  slv += __shfl_xor(slv, 2);
  const float cost = (bvo + 0.5f * slv) * rsum;
  const float aj = 1.0f / (1.0f + __expf(-inv_temp * (bao - cost)));

  if (MODE == 2) {
    if (wv == 0) {
      float* ob = out + ((size_t)(pid * 16 + o) << 4) + r;
      ob[0] = m0; ob[4] = m1; ob[8] = m2; ob[12] = m3;
      if (r == 0) out[(size_t)B_ * P2_ * O_ * 16 + pid * 16 + o] = aj;
    }
    return;
  }

  // ---- pass 2: z[k][o] from cached votes (no loads) ----
  const float iv0 = 1.0f / va0, iv1 = 1.0f / va1, iv2 = 1.0f / va2, iv3 = 1.0f / va3;
  const float Cz = __logf(aj + EPS_) - 0.5f * (slv + 16.0f * LOG2PI_);
  float* zo = zout + (size_t)pid * NV_ + ((kk * 16) << 4) + o;
#pragma unroll
  for (int ci = 0; ci < 16; ++ci) {
    const float d0 = vreg[ci][0] - m0, d1 = vreg[ci][1] - m1;
    const float d2 = vreg[ci][2] - m2, d3 = vreg[ci][3] - m3;
    float q = d0 * d0 * iv0 + d1 * d1 * iv1 + d2 * d2 * iv2 + d3 * d3 * iv3;
    q += __shfl_xor(q, 1);
    q += __shfl_xor(q, 2);
    if (r == 0) zo[ci << 4] = Cz - 0.5f * q;  // 16 lanes -> one 64B line
  }
}

// 4 threads per segment (b,h,w,ci); z cached in registers between max and sum.
__global__ __launch_bounds__(256) void seg_reduce(const float* __restrict__ z,
                                                  float* __restrict__ gmax,
                                                  float* __restrict__ gden) {
  const int tid = blockIdx.x * 256 + threadIdx.x;  // 0..131071
  const int part = tid & 3, ci = (tid >> 2) & 15, w2 = (tid >> 6) & 15;
  const int h = (tid >> 10) & 15, b = tid >> 14;
  float4 v[9];
  float m = -3.0e38f;
#pragma unroll
  for (int s = 0; s < 9; ++s) {
    const int ki = (s >= 6) ? 2 : (s >= 3) ? 1 : 0, kj = s - 3 * ki;
    const int pi = h - ki, pj = w2 - kj;
    if ((unsigned)pi < (unsigned)P_ && (unsigned)pj < (unsigned)P_) {
      v[s] = *(const float4*)(z + (size_t)(b * P2_ + pi * P_ + pj) * NV_ + s * 256 +
                              ci * 16 + part * 4);
    } else {
      v[s] = make_float4(-3.0e38f, -3.0e38f, -3.0e38f, -3.0e38f);
    }
    m = fmaxf(m, fmaxf(fmaxf(v[s].x, v[s].y), fmaxf(v[s].z, v[s].w)));
  }
  m = fmaxf(m, __shfl_xor(m, 1));
  m = fmaxf(m, __shfl_xor(m, 2));
  float s_ = 0.f;
#pragma unroll
  for (int s = 0; s < 9; ++s) {
    s_ += __expf(v[s].x - m) + __expf(v[s].y - m) + __expf(v[s].z - m) + __expf(v[s].w - m);
  }
  s_ += __shfl_xor(s_, 1);
  s_ += __shfl_xor(s_, 2);
  if (part == 0) {
    gmax[tid >> 2] = m;
    gden[tid >> 2] = s_;
  }
}
}  // namespace

extern "C" void kernel_launch(void* const* d_in, const int* in_sizes, int n_in,
                              void* d_out, int out_size, void* d_ws, size_t ws_size,
                              hipStream_t stream) {
  const float* pose = (const float*)d_in[0];
  const float* act = (const float*)d_in[1];
  const float* w = (const float*)d_in[2];
  const float* ba = (const float*)d_in[3];
  const float* bv = (const float*)d_in[4];
  float* out = (float*)d_out;

  float* z = (float*)d_ws;                  // 3,612,672 floats, layout [pid][k][o]
  float* gm = z + (size_t)B_ * P2_ * NV_;   // 32,768
  float* gd = gm + B_ * H_ * H_ * CI_;      // 32,768
  float* wt = gd + B_ * H_ * H_ * CI_;      // 36,864

  const int NB = B_ * P2_;  // 1568 blocks, one per patch
  transpose_w<<<144, 256, 0, stream>>>(w, wt);
  caps_main<0><<<NB, 576, 0, stream>>>(pose, act, wt, ba, bv, z, gm, gd, z, out);
  seg_reduce<<<512, 256, 0, stream>>>(z, gm, gd);
  caps_main<1><<<NB, 576, 0, stream>>>(pose, act, wt, ba, bv, z, gm, gd, z, out);
  seg_reduce<<<512, 256, 0, stream>>>(z, gm, gd);
  caps_main<2><<<NB, 576, 0, stream>>>(pose, act, wt, ba, bv, z, gm, gd, z, out);
}

// Round 8
// 174.703 us; speedup vs baseline: 1.5598x; 1.5598x over previous
//
#include <hip/hip_runtime.h>

namespace {
constexpr int B_ = 8, H_ = 16, CI_ = 16, O_ = 16, P_ = 14;
constexpr int P2_ = P_ * P_;    // 196
constexpr int K2CI_ = 144;
constexpr int NV_ = 2304;       // z per patch, layout [k][o]
constexpr float EPS_ = 1e-9f;
constexpr float LOG2PI_ = 1.8378770664093453f;

__device__ __forceinline__ float cnt1(int h) {
  int lo = (h - (P_ - 1)) > 0 ? (h - (P_ - 1)) : 0;
  int hi = h < 2 ? h : 2;
  return (float)(hi - lo + 1);
}

// wt[k][o][r][q] = w[k][o][q][r]
__global__ __launch_bounds__(256) void transpose_w(const float* __restrict__ w,
                                                   float* __restrict__ wt) {
  const int i = blockIdx.x * 256 + threadIdx.x;
  const int ko = i >> 4, q = (i >> 2) & 3, r = i & 3;
  wt[(ko << 4) + (r << 2) + q] = w[i];
}

// One BLOCK (512 thr, 8 waves) per patch. Wave wv owns ci in {2wv, 2wv+1} across all 9 kk
// (kk-loop unrolled: ki,kj compile-time, bases are block-uniform + constant offsets; pose
// addresses are wave-uniform -> scalarizable). lane = o*4 + r ; dims d = p*4+r.
// MODE 0: rr uniform -> z. MODE 1: rr softmax -> z. MODE 2: rr softmax -> outputs.
template <int MODE>
__global__ __launch_bounds__(512, 8) void caps_main(
    const float* __restrict__ pose, const float* __restrict__ act,
    const float* __restrict__ wt, const float* __restrict__ beta_a,
    const float* __restrict__ beta_v, const float* __restrict__ zin,
    const float* __restrict__ gmax, const float* __restrict__ gden,
    float* __restrict__ zout, float* __restrict__ out) {
  __shared__ float rr_s[(MODE == 0) ? K2CI_ : NV_];  // MODE0: rr0[k] ; else rr[k][o]
  __shared__ float part[9][512];                     // Welford partials [stat][wv*64+l]
  __shared__ float gm_s[(MODE == 0) ? 1 : K2CI_];
  __shared__ float ad_s[(MODE == 0) ? 1 : K2CI_];

  const int tid = threadIdx.x;
  const int wv = __builtin_amdgcn_readfirstlane(tid >> 6);
  const int l = tid & 63;
  const int o = l >> 2, r = l & 3;
  const int pid = blockIdx.x;
  const int b = pid / P2_;
  const int p2 = pid - b * P2_;
  const int pi = p2 / P_;
  const int pj = p2 - pi * P_;
  const float inv_temp = (MODE == 0) ? 0.0005f : (MODE == 1) ? 0.000975f : 0.00142625f;

  // ---- prologue: stage rr (or gmax/act-den) into LDS ----
  if (MODE == 0) {
    if (tid < K2CI_) {
      const int ci = tid & 15, kk = tid >> 4;
      const int ki = (kk >= 6) ? 2 : (kk >= 3) ? 1 : 0, kj = kk - 3 * ki;
      const int cidx = ((b * H_ + pi + ki) * H_ + pj + kj) * CI_ + ci;
      rr_s[tid] = act[cidx] / (16.0f * cnt1(pi + ki) * cnt1(pj + kj));
    }
  } else {
    if (tid < K2CI_) {
      const int ci = tid & 15, kk = tid >> 4;
      const int ki = (kk >= 6) ? 2 : (kk >= 3) ? 1 : 0, kj = kk - 3 * ki;
      const int cidx = ((b * H_ + pi + ki) * H_ + pj + kj) * CI_ + ci;
      gm_s[tid] = gmax[cidx];
      ad_s[tid] = act[cidx] / (gden[cidx] + EPS_);
    }
    __syncthreads();
    for (int i4 = tid; i4 < NV_ / 4; i4 += 512) {
      const float4 z4 = ((const float4*)(zin + (size_t)pid * NV_))[i4];
      const int k = i4 >> 2;
      const float gmk = gm_s[k], adk = ad_s[k];
      float4 r4;
      r4.x = __expf(z4.x - gmk) * adk;
      r4.y = __expf(z4.y - gmk) * adk;
      r4.z = __expf(z4.z - gmk) * adk;
      r4.w = __expf(z4.w - gmk) * adk;
      ((float4*)rr_s)[i4] = r4;
    }
  }
  __syncthreads();

  const float bvo = 16.0f * beta_v[o];
  const float bao = beta_a[o];

  // block-uniform bases; per-kk offsets are compile-time constants after unroll
  const float* pose_b = pose + ((size_t)((b * H_ + pi) * H_ + pj) << 8);
  const float* wt_l = wt + (l << 2);
  const int ci0 = wv * 2;

  // ---- pass 1: fused mean+var partials over this wave's 18 (kk,ci) ----
  float prr = 0.f;
  float pm0 = 0.f, pm1 = 0.f, pm2 = 0.f, pm3 = 0.f;
  float pv0 = 0.f, pv1 = 0.f, pv2 = 0.f, pv3 = 0.f;
#pragma unroll
  for (int kk = 0; kk < 9; ++kk) {
    const int ki = kk / 3, kj = kk - 3 * (kk / 3);
    const float* pb = pose_b + ((ki * H_ + kj) << 8);
    const float* wb = wt_l + ((size_t)kk << 12);
#pragma unroll
    for (int c = 0; c < 2; ++c) {
      const int ci = ci0 + c;
      const float4 w4 = *(const float4*)(wb + (ci << 8));
      const float4 Pa = *(const float4*)(pb + (ci << 4));
      const float4 Pb = *(const float4*)(pb + (ci << 4) + 4);
      const float4 Pc = *(const float4*)(pb + (ci << 4) + 8);
      const float4 Pd = *(const float4*)(pb + (ci << 4) + 12);
      const float v0 = Pa.x * w4.x + Pa.y * w4.y + Pa.z * w4.z + Pa.w * w4.w;
      const float v1 = Pb.x * w4.x + Pb.y * w4.y + Pb.z * w4.z + Pb.w * w4.w;
      const float v2 = Pc.x * w4.x + Pc.y * w4.y + Pc.z * w4.z + Pc.w * w4.w;
      const float v3 = Pd.x * w4.x + Pd.y * w4.y + Pd.z * w4.z + Pd.w * w4.w;
      const float rrk =
          (MODE == 0) ? rr_s[kk * 16 + ci] : rr_s[((kk * 16 + ci) << 4) + o];
      prr += rrk;
      const float a0 = rrk * v0, a1 = rrk * v1, a2 = rrk * v2, a3 = rrk * v3;
      pm0 += a0; pm1 += a1; pm2 += a2; pm3 += a3;
      pv0 = fmaf(a0, v0, pv0); pv1 = fmaf(a1, v1, pv1);
      pv2 = fmaf(a2, v2, pv2); pv3 = fmaf(a3, v3, pv3);
    }
  }
  // ---- combine partials across 8 waves via LDS (stride-1, conflict-free) ----
  part[0][tid] = prr;
  part[1][tid] = pm0; part[2][tid] = pm1; part[3][tid] = pm2; part[4][tid] = pm3;
  part[5][tid] = pv0; part[6][tid] = pv1; part[7][tid] = pv2; part[8][tid] = pv3;
  __syncthreads();
  float s[9];
#pragma unroll
  for (int j = 0; j < 9; ++j) {
    float acc = part[j][l];
#pragma unroll
    for (int wvi = 1; wvi < 8; ++wvi) acc += part[j][wvi * 64 + l];
    s[j] = acc;
  }
  const float rsum = s[0] + EPS_;
  const float irs = 1.0f / rsum;
  const float m0 = s[1] * irs, m1 = s[2] * irs, m2 = s[3] * irs, m3 = s[4] * irs;
  const float va0 = fmaxf(s[5] * irs - m0 * m0, 0.f) + EPS_;
  const float va1 = fmaxf(s[6] * irs - m1 * m1, 0.f) + EPS_;
  const float va2 = fmaxf(s[7] * irs - m2 * m2, 0.f) + EPS_;
  const float va3 = fmaxf(s[8] * irs - m3 * m3, 0.f) + EPS_;
  float slv = __logf(va0) + __logf(va1) + __logf(va2) + __logf(va3);
  slv += __shfl_xor(slv, 1);
  slv += __shfl_xor(slv, 2);
  const float cost = (bvo + 0.5f * slv) * rsum;
  const float aj = 1.0f / (1.0f + __expf(-inv_temp * (bao - cost)));

  if (MODE == 2) {
    if (wv == 0) {
      float* ob = out + ((size_t)(pid * 16 + o) << 4) + r;
      ob[0] = m0; ob[4] = m1; ob[8] = m2; ob[12] = m3;
      if (r == 0) out[(size_t)B_ * P2_ * O_ * 16 + pid * 16 + o] = aj;
    }
    return;
  }

  // ---- pass 2: recompute votes (L1-hot), write z[k][o] ----
  const float iv0 = 1.0f / va0, iv1 = 1.0f / va1, iv2 = 1.0f / va2, iv3 = 1.0f / va3;
  const float Cz = __logf(aj + EPS_) - 0.5f * (slv + 16.0f * LOG2PI_);
  float* zo = zout + (size_t)pid * NV_ + o;
#pragma unroll
  for (int kk = 0; kk < 9; ++kk) {
    const int ki = kk / 3, kj = kk - 3 * (kk / 3);
    const float* pb = pose_b + ((ki * H_ + kj) << 8);
    const float* wb = wt_l + ((size_t)kk << 12);
#pragma unroll
    for (int c = 0; c < 2; ++c) {
      const int ci = ci0 + c;
      const float4 w4 = *(const float4*)(wb + (ci << 8));
      const float4 Pa = *(const float4*)(pb + (ci << 4));
      const float4 Pb = *(const float4*)(pb + (ci << 4) + 4);
      const float4 Pc = *(const float4*)(pb + (ci << 4) + 8);
      const float4 Pd = *(const float4*)(pb + (ci << 4) + 12);
      const float v0 = Pa.x * w4.x + Pa.y * w4.y + Pa.z * w4.z + Pa.w * w4.w;
      const float v1 = Pb.x * w4.x + Pb.y * w4.y + Pb.z * w4.z + Pb.w * w4.w;
      const float v2 = Pc.x * w4.x + Pc.y * w4.y + Pc.z * w4.z + Pc.w * w4.w;
      const float v3 = Pd.x * w4.x + Pd.y * w4.y + Pd.z * w4.z + Pd.w * w4.w;
      const float d0 = v0 - m0, d1 = v1 - m1, d2 = v2 - m2, d3 = v3 - m3;
      float q = d0 * d0 * iv0 + d1 * d1 * iv1 + d2 * d2 * iv2 + d3 * d3 * iv3;
      q += __shfl_xor(q, 1);
      q += __shfl_xor(q, 2);
      if (r == 0) zo[(kk * 16 + ci) << 4] = Cz - 0.5f * q;  // 16 lanes -> one 64B line
    }
  }
}

// 4 threads per segment (b,h,w,ci); z cached in registers between max and sum.
__global__ __launch_bounds__(256) void seg_reduce(const float* __restrict__ z,
                                                  float* __restrict__ gmax,
                                                  float* __restrict__ gden) {
  const int tid = blockIdx.x * 256 + threadIdx.x;  // 0..131071
  const int part = tid & 3, ci = (tid >> 2) & 15, w2 = (tid >> 6) & 15;
  const int h = (tid >> 10) & 15, b = tid >> 14;
  float4 v[9];
  float m = -3.0e38f;
#pragma unroll
  for (int s = 0; s < 9; ++s) {
    const int ki = (s >= 6) ? 2 : (s >= 3) ? 1 : 0, kj = s - 3 * ki;
    const int pi = h - ki, pj = w2 - kj;
    if ((unsigned)pi < (unsigned)P_ && (unsigned)pj < (unsigned)P_) {
      v[s] = *(const float4*)(z + (size_t)(b * P2_ + pi * P_ + pj) * NV_ + s * 256 +
                              ci * 16 + part * 4);
    } else {
      v[s] = make_float4(-3.0e38f, -3.0e38f, -3.0e38f, -3.0e38f);
    }
    m = fmaxf(m, fmaxf(fmaxf(v[s].x, v[s].y), fmaxf(v[s].z, v[s].w)));
  }
  m = fmaxf(m, __shfl_xor(m, 1));
  m = fmaxf(m, __shfl_xor(m, 2));
  float s_ = 0.f;
#pragma unroll
  for (int s = 0; s < 9; ++s) {
    s_ += __expf(v[s].x - m) + __expf(v[s].y - m) + __expf(v[s].z - m) + __expf(v[s].w - m);
  }
  s_ += __shfl_xor(s_, 1);
  s_ += __shfl_xor(s_, 2);
  if (part == 0) {
    gmax[tid >> 2] = m;
    gden[tid >> 2] = s_;
  }
}
}  // namespace

extern "C" void kernel_launch(void* const* d_in, const int* in_sizes, int n_in,
                              void* d_out, int out_size, void* d_ws, size_t ws_size,
                              hipStream_t stream) {
  const float* pose = (const float*)d_in[0];
  const float* act = (const float*)d_in[1];
  const float* w = (const float*)d_in[2];
  const float* ba = (const float*)d_in[3];
  const float* bv = (const float*)d_in[4];
  float* out = (float*)d_out;

  float* z = (float*)d_ws;                  // 3,612,672 floats, layout [pid][k][o]
  float* gm = z + (size_t)B_ * P2_ * NV_;   // 32,768
  float* gd = gm + B_ * H_ * H_ * CI_;      // 32,768
  float* wt = gd + B_ * H_ * H_ * CI_;      // 36,864

  const int NB = B_ * P2_;  // 1568 blocks, one per patch
  transpose_w<<<144, 256, 0, stream>>>(w, wt);
  caps_main<0><<<NB, 512, 0, stream>>>(pose, act, wt, ba, bv, z, gm, gd, z, out);
  seg_reduce<<<512, 256, 0, stream>>>(z, gm, gd);
  caps_main<1><<<NB, 512, 0, stream>>>(pose, act, wt, ba, bv, z, gm, gd, z, out);
  seg_reduce<<<512, 256, 0, stream>>>(z, gm, gd);
  caps_main<2><<<NB, 512, 0, stream>>>(pose, act, wt, ba, bv, z, gm, gd, z, out);
}

// Round 9
// 166.058 us; speedup vs baseline: 1.6410x; 1.0521x over previous
//
#include <hip/hip_runtime.h>

namespace {
constexpr int B_ = 8, H_ = 16, CI_ = 16, O_ = 16, P_ = 14;
constexpr int P2_ = P_ * P_;    // 196
constexpr int K2CI_ = 144;
constexpr int NV_ = 2304;       // z per patch, layout [k][o]
constexpr float EPS_ = 1e-9f;
constexpr float LOG2PI_ = 1.8378770664093453f;

using f2 = __attribute__((ext_vector_type(2))) float;

__device__ __forceinline__ float cnt1(int h) {
  int lo = (h - (P_ - 1)) > 0 ? (h - (P_ - 1)) : 0;
  int hi = h < 2 ? h : 2;
  return (float)(hi - lo + 1);
}

// wt[k][o][r][q] = w[k][o][q][r]
__global__ __launch_bounds__(256) void transpose_w(const float* __restrict__ w,
                                                   float* __restrict__ wt) {
  const int i = blockIdx.x * 256 + threadIdx.x;
  const int ko = i >> 4, q = (i >> 2) & 3, r = i & 3;
  wt[(ko << 4) + (r << 2) + q] = w[i];
}

// pose_t[cell][q][p] = pose[cell][p][q]  (4x4 transpose per cell) -> p-pairs adjacent
__global__ __launch_bounds__(256) void transpose_pose(const float* __restrict__ pose,
                                                      float* __restrict__ pose_t) {
  const int i = blockIdx.x * 256 + threadIdx.x;  // 0..524287
  const int cell = i >> 4, idx = i & 15;
  const int p = idx >> 2, q = idx & 3;
  pose_t[(cell << 4) + (q << 2) + p] = pose[i];
}

// packed vote dot: v01 = {v[p0],v[p1]}, v23 = {v[p2],v[p3]} for this lane's r
__device__ __forceinline__ void vote_dot(const float* __restrict__ pb, const float4 w4,
                                         f2& v01, f2& v23) {
  const f2 A0 = *(const f2*)(pb + 0), B0 = *(const f2*)(pb + 2);
  const f2 A1 = *(const f2*)(pb + 4), B1 = *(const f2*)(pb + 6);
  const f2 A2 = *(const f2*)(pb + 8), B2 = *(const f2*)(pb + 10);
  const f2 A3 = *(const f2*)(pb + 12), B3 = *(const f2*)(pb + 14);
  v01 = A0 * w4.x;
  v23 = B0 * w4.x;
  v01 = __builtin_elementwise_fma(A1, (f2){w4.y, w4.y}, v01);
  v23 = __builtin_elementwise_fma(B1, (f2){w4.y, w4.y}, v23);
  v01 = __builtin_elementwise_fma(A2, (f2){w4.z, w4.z}, v01);
  v23 = __builtin_elementwise_fma(B2, (f2){w4.z, w4.z}, v23);
  v01 = __builtin_elementwise_fma(A3, (f2){w4.w, w4.w}, v01);
  v23 = __builtin_elementwise_fma(B3, (f2){w4.w, w4.w}, v23);
}

// One BLOCK (512 thr, 8 waves) per patch. Wave wv owns ci in {2wv,2wv+1} across all 9 kk.
// lane = o*4 + r ; lane covers dims d = p*4+r. Packed-fp32 math over p-pairs.
// MODE 0: rr uniform -> z. MODE 1: rr softmax -> z. MODE 2: rr softmax -> outputs.
template <int MODE>
__global__ __launch_bounds__(512, 8) void caps_main(
    const float* __restrict__ pose_t, const float* __restrict__ act,
    const float* __restrict__ wt, const float* __restrict__ beta_a,
    const float* __restrict__ beta_v, const float* __restrict__ zin,
    const float* __restrict__ gmax, const float* __restrict__ gden,
    float* __restrict__ zout, float* __restrict__ out) {
  __shared__ float rr_s[(MODE == 0) ? K2CI_ : NV_];  // MODE0: rr0[k] ; else rr[k][o]
  __shared__ f2 partv[4][512];                       // pm01, pm23, pv01, pv23
  __shared__ float partr[512];                       // prr
  __shared__ f2 sfin[4][64];
  __shared__ float sfr[64];
  __shared__ float gm_s[(MODE == 0) ? 1 : K2CI_];
  __shared__ float ad_s[(MODE == 0) ? 1 : K2CI_];

  const int tid = threadIdx.x;
  const int wv = __builtin_amdgcn_readfirstlane(tid >> 6);
  const int l = tid & 63;
  const int o = l >> 2, r = l & 3;
  const int pid = blockIdx.x;
  const int b = pid / P2_;
  const int p2 = pid - b * P2_;
  const int pi = p2 / P_;
  const int pj = p2 - pi * P_;
  const float inv_temp = (MODE == 0) ? 0.0005f : (MODE == 1) ? 0.000975f : 0.00142625f;

  // ---- prologue: stage rr (or gmax/act-den) into LDS ----
  if (MODE == 0) {
    if (tid < K2CI_) {
      const int ci = tid & 15, kk = tid >> 4;
      const int ki = (kk >= 6) ? 2 : (kk >= 3) ? 1 : 0, kj = kk - 3 * ki;
      const int cidx = ((b * H_ + pi + ki) * H_ + pj + kj) * CI_ + ci;
      rr_s[tid] = act[cidx] / (16.0f * cnt1(pi + ki) * cnt1(pj + kj));
    }
  } else {
    if (tid < K2CI_) {
      const int ci = tid & 15, kk = tid >> 4;
      const int ki = (kk >= 6) ? 2 : (kk >= 3) ? 1 : 0, kj = kk - 3 * ki;
      const int cidx = ((b * H_ + pi + ki) * H_ + pj + kj) * CI_ + ci;
      gm_s[tid] = gmax[cidx];
      ad_s[tid] = act[cidx] / (gden[cidx] + EPS_);
    }
    __syncthreads();
    for (int i4 = tid; i4 < NV_ / 4; i4 += 512) {
      const float4 z4 = ((const float4*)(zin + (size_t)pid * NV_))[i4];
      const int k = i4 >> 2;
      const float gmk = gm_s[k], adk = ad_s[k];
      float4 r4;
      r4.x = __expf(z4.x - gmk) * adk;
      r4.y = __expf(z4.y - gmk) * adk;
      r4.z = __expf(z4.z - gmk) * adk;
      r4.w = __expf(z4.w - gmk) * adk;
      ((float4*)rr_s)[i4] = r4;
    }
  }
  __syncthreads();

  const float bvo = 16.0f * beta_v[o];
  const float bao = beta_a[o];

  // block-uniform bases; per-kk offsets compile-time after unroll
  const float* pose_b = pose_t + ((size_t)((b * H_ + pi) * H_ + pj) << 8);
  const float* wt_l = wt + (l << 2);
  const int ci0 = wv * 2;

  // ---- pass 1: packed fused mean+var partials over this wave's 18 (kk,ci) ----
  float prr = 0.f;
  f2 pm01 = {0.f, 0.f}, pm23 = {0.f, 0.f}, pv01 = {0.f, 0.f}, pv23 = {0.f, 0.f};
#pragma unroll
  for (int kk = 0; kk < 9; ++kk) {
    const int ki = kk / 3, kj = kk - 3 * (kk / 3);
    const float* pbase = pose_b + ((ki * H_ + kj) << 8);
    const float* wb = wt_l + ((size_t)kk << 12);
#pragma unroll
    for (int c = 0; c < 2; ++c) {
      const int ci = ci0 + c;
      const float4 w4 = *(const float4*)(wb + (ci << 8));
      f2 v01, v23;
      vote_dot(pbase + (ci << 4), w4, v01, v23);
      const float rrk =
          (MODE == 0) ? rr_s[kk * 16 + ci] : rr_s[((kk * 16 + ci) << 4) + o];
      prr += rrk;
      const f2 rr2 = {rrk, rrk};
      const f2 a01 = rr2 * v01, a23 = rr2 * v23;
      pm01 += a01;
      pm23 += a23;
      pv01 = __builtin_elementwise_fma(a01, v01, pv01);
      pv23 = __builtin_elementwise_fma(a23, v23, pv23);
    }
  }
  // ---- two-stage cross-wave combine ----
  partv[0][tid] = pm01; partv[1][tid] = pm23;
  partv[2][tid] = pv01; partv[3][tid] = pv23;
  partr[tid] = prr;
  __syncthreads();
  if (tid < 320) {
    if (tid < 256) {
      const int st = tid >> 6, li = tid & 63;
      f2 acc = partv[st][li];
#pragma unroll
      for (int wvi = 1; wvi < 8; ++wvi) acc += partv[st][wvi * 64 + li];
      sfin[st][li] = acc;
    } else {
      const int li = tid & 63;
      float acc = partr[li];
#pragma unroll
      for (int wvi = 1; wvi < 8; ++wvi) acc += partr[wvi * 64 + li];
      sfr[li] = acc;
    }
  }
  __syncthreads();
  const f2 S01 = sfin[0][l], S23 = sfin[1][l];
  const f2 V01 = sfin[2][l], V23 = sfin[3][l];
  const float rsum = sfr[l] + EPS_;
  const float irs = 1.0f / rsum;
  const f2 irs2 = {irs, irs};
  const f2 m01 = S01 * irs2, m23 = S23 * irs2;
  const f2 zero2 = {0.f, 0.f}, eps2 = {EPS_, EPS_};
  const f2 va01 = __builtin_elementwise_max(V01 * irs2 - m01 * m01, zero2) + eps2;
  const f2 va23 = __builtin_elementwise_max(V23 * irs2 - m23 * m23, zero2) + eps2;
  float slv = __logf(va01.x) + __logf(va01.y) + __logf(va23.x) + __logf(va23.y);
  slv += __shfl_xor(slv, 1);
  slv += __shfl_xor(slv, 2);
  const float cost = (bvo + 0.5f * slv) * rsum;
  const float aj = 1.0f / (1.0f + __expf(-inv_temp * (bao - cost)));

  if (MODE == 2) {
    if (wv == 0) {
      float* ob = out + ((size_t)(pid * 16 + o) << 4) + r;
      ob[0] = m01.x; ob[4] = m01.y; ob[8] = m23.x; ob[12] = m23.y;
      if (r == 0) out[(size_t)B_ * P2_ * O_ * 16 + pid * 16 + o] = aj;
    }
    return;
  }

  // ---- pass 2: recompute votes (packed), write z[k][o] ----
  const f2 iv01 = {1.0f / va01.x, 1.0f / va01.y};
  const f2 iv23 = {1.0f / va23.x, 1.0f / va23.y};
  const float Cz = __logf(aj + EPS_) - 0.5f * (slv + 16.0f * LOG2PI_);
  float* zo = zout + (size_t)pid * NV_ + o;
#pragma unroll
  for (int kk = 0; kk < 9; ++kk) {
    const int ki = kk / 3, kj = kk - 3 * (kk / 3);
    const float* pbase = pose_b + ((ki * H_ + kj) << 8);
    const float* wb = wt_l + ((size_t)kk << 12);
#pragma unroll
    for (int c = 0; c < 2; ++c) {
      const int ci = ci0 + c;
      const float4 w4 = *(const float4*)(wb + (ci << 8));
      f2 v01, v23;
      vote_dot(pbase + (ci << 4), w4, v01, v23);
      const f2 d01 = v01 - m01, d23 = v23 - m23;
      const f2 q2 = __builtin_elementwise_fma(d01 * d01, iv01, (d23 * d23) * iv23);
      float q = q2.x + q2.y;
      q += __shfl_xor(q, 1);
      q += __shfl_xor(q, 2);
      if (r == 0) zo[(kk * 16 + ci) << 4] = Cz - 0.5f * q;  // 16 lanes -> one 64B line
    }
  }
}

// 4 threads per segment (b,h,w,ci); z cached in registers between max and sum.
__global__ __launch_bounds__(256) void seg_reduce(const float* __restrict__ z,
                                                  float* __restrict__ gmax,
                                                  float* __restrict__ gden) {
  const int tid = blockIdx.x * 256 + threadIdx.x;  // 0..131071
  const int part = tid & 3, ci = (tid >> 2) & 15, w2 = (tid >> 6) & 15;
  const int h = (tid >> 10) & 15, b = tid >> 14;
  float4 v[9];
  float m = -3.0e38f;
#pragma unroll
  for (int s = 0; s < 9; ++s) {
    const int ki = (s >= 6) ? 2 : (s >= 3) ? 1 : 0, kj = s - 3 * ki;
    const int pi = h - ki, pj = w2 - kj;
    if ((unsigned)pi < (unsigned)P_ && (unsigned)pj < (unsigned)P_) {
      v[s] = *(const float4*)(z + (size_t)(b * P2_ + pi * P_ + pj) * NV_ + s * 256 +
                              ci * 16 + part * 4);
    } else {
      v[s] = make_float4(-3.0e38f, -3.0e38f, -3.0e38f, -3.0e38f);
    }
    m = fmaxf(m, fmaxf(fmaxf(v[s].x, v[s].y), fmaxf(v[s].z, v[s].w)));
  }
  m = fmaxf(m, __shfl_xor(m, 1));
  m = fmaxf(m, __shfl_xor(m, 2));
  float s_ = 0.f;
#pragma unroll
  for (int s = 0; s < 9; ++s) {
    s_ += __expf(v[s].x - m) + __expf(v[s].y - m) + __expf(v[s].z - m) + __expf(v[s].w - m);
  }
  s_ += __shfl_xor(s_, 1);
  s_ += __shfl_xor(s_, 2);
  if (part == 0) {
    gmax[tid >> 2] = m;
    gden[tid >> 2] = s_;
  }
}
}  // namespace

extern "C" void kernel_launch(void* const* d_in, const int* in_sizes, int n_in,
                              void* d_out, int out_size, void* d_ws, size_t ws_size,
                              hipStream_t stream) {
  const float* pose = (const float*)d_in[0];
  const float* act = (const float*)d_in[1];
  const float* w = (const float*)d_in[2];
  const float* ba = (const float*)d_in[3];
  const float* bv = (const float*)d_in[4];
  float* out = (float*)d_out;

  float* z = (float*)d_ws;                  // 3,612,672 floats, layout [pid][k][o]
  float* gm = z + (size_t)B_ * P2_ * NV_;   // 32,768
  float* gd = gm + B_ * H_ * H_ * CI_;      // 32,768
  float* wt = gd + B_ * H_ * H_ * CI_;      // 36,864
  float* pt = wt + 36864;                   // 524,288 (pose transposed)

  const int NB = B_ * P2_;  // 1568 blocks, one per patch
  transpose_w<<<144, 256, 0, stream>>>(w, wt);
  transpose_pose<<<2048, 256, 0, stream>>>(pose, pt);
  caps_main<0><<<NB, 512, 0, stream>>>(pt, act, wt, ba, bv, z, gm, gd, z, out);
  seg_reduce<<<512, 256, 0, stream>>>(z, gm, gd);
  caps_main<1><<<NB, 512, 0, stream>>>(pt, act, wt, ba, bv, z, gm, gd, z, out);
  seg_reduce<<<512, 256, 0, stream>>>(z, gm, gd);
  caps_main<2><<<NB, 512, 0, stream>>>(pt, act, wt, ba, bv, z, gm, gd, z, out);
}

// Round 10
// 165.111 us; speedup vs baseline: 1.6504x; 1.0057x over previous
//
#include <hip/hip_runtime.h>

namespace {
constexpr int B_ = 8, H_ = 16, CI_ = 16, O_ = 16, P_ = 14;
constexpr int P2_ = P_ * P_;    // 196
constexpr int K2CI_ = 144;
constexpr int NV_ = 2304;       // z per patch, layout [k][o]
constexpr float EPS_ = 1e-9f;
constexpr float LOG2PI_ = 1.8378770664093453f;

using f2 = __attribute__((ext_vector_type(2))) float;

__device__ __forceinline__ float cnt1(int h) {
  int lo = (h - (P_ - 1)) > 0 ? (h - (P_ - 1)) : 0;
  int hi = h < 2 ? h : 2;
  return (float)(hi - lo + 1);
}

// Fused prologue: blocks [0,2048) transpose pose (4x4 per cell -> [q][p]);
// blocks [2048,2192) transpose w -> wt[k][o][r][q].
__global__ __launch_bounds__(256) void transpose_all(const float* __restrict__ pose,
                                                     float* __restrict__ pose_t,
                                                     const float* __restrict__ w,
                                                     float* __restrict__ wt) {
  if (blockIdx.x < 2048) {
    const int i = blockIdx.x * 256 + threadIdx.x;  // 0..524287
    const int cell = i >> 4, idx = i & 15;
    const int p = idx >> 2, q = idx & 3;
    pose_t[(cell << 4) + (q << 2) + p] = pose[i];
  } else {
    const int i = (blockIdx.x - 2048) * 256 + threadIdx.x;  // 0..36863
    const int ko = i >> 4, q = (i >> 2) & 3, r = i & 3;
    wt[(ko << 4) + (r << 2) + q] = w[i];
  }
}

// One BLOCK (512 thr, 8 waves) per patch. Wave wv owns ci in {2wv,2wv+1} across all 9 kk.
// lane = o*4 + r ; lane covers dims d = p*4+r. Packed-fp32 math; depth-2 prefetch on wt.
// MODE 0: rr uniform -> z. MODE 1: rr softmax -> z. MODE 2: rr softmax -> outputs.
template <int MODE>
__global__ __launch_bounds__(512, 8) void caps_main(
    const float* __restrict__ pose_t, const float* __restrict__ act,
    const float* __restrict__ wt, const float* __restrict__ beta_a,
    const float* __restrict__ beta_v, const float* __restrict__ zin,
    const float* __restrict__ gmax, const float* __restrict__ gden,
    float* __restrict__ zout, float* __restrict__ out) {
  __shared__ float rr_s[(MODE == 0) ? K2CI_ : NV_];  // MODE0: rr0[k] ; else rr[k][o]
  __shared__ f2 partv[4][512];                       // pm01, pm23, pv01, pv23
  __shared__ float partr[512];                       // prr
  __shared__ f2 sfin[4][64];
  __shared__ float sfr[64];
  __shared__ float gm_s[(MODE == 0) ? 1 : K2CI_];
  __shared__ float ad_s[(MODE == 0) ? 1 : K2CI_];

  const int tid = threadIdx.x;
  const int wv = __builtin_amdgcn_readfirstlane(tid >> 6);
  const int l = tid & 63;
  const int o = l >> 2, r = l & 3;
  const int pid = blockIdx.x;
  const int b = pid / P2_;
  const int p2 = pid - b * P2_;
  const int pi = p2 / P_;
  const int pj = p2 - pi * P_;
  const float inv_temp = (MODE == 0) ? 0.0005f : (MODE == 1) ? 0.000975f : 0.00142625f;

  // ---- prologue: stage rr (or gmax/act-den) into LDS ----
  if (MODE == 0) {
    if (tid < K2CI_) {
      const int ci = tid & 15, kk = tid >> 4;
      const int ki = (kk >= 6) ? 2 : (kk >= 3) ? 1 : 0, kj = kk - 3 * ki;
      const int cidx = ((b * H_ + pi + ki) * H_ + pj + kj) * CI_ + ci;
      rr_s[tid] = act[cidx] / (16.0f * cnt1(pi + ki) * cnt1(pj + kj));
    }
  } else {
    if (tid < K2CI_) {
      const int ci = tid & 15, kk = tid >> 4;
      const int ki = (kk >= 6) ? 2 : (kk >= 3) ? 1 : 0, kj = kk - 3 * ki;
      const int cidx = ((b * H_ + pi + ki) * H_ + pj + kj) * CI_ + ci;
      gm_s[tid] = gmax[cidx];
      ad_s[tid] = act[cidx] / (gden[cidx] + EPS_);
    }
    __syncthreads();
    for (int i4 = tid; i4 < NV_ / 4; i4 += 512) {
      const float4 z4 = ((const float4*)(zin + (size_t)pid * NV_))[i4];
      const int k = i4 >> 2;
      const float gmk = gm_s[k], adk = ad_s[k];
      float4 r4;
      r4.x = __expf(z4.x - gmk) * adk;
      r4.y = __expf(z4.y - gmk) * adk;
      r4.z = __expf(z4.z - gmk) * adk;
      r4.w = __expf(z4.w - gmk) * adk;
      ((float4*)rr_s)[i4] = r4;
    }
  }
  __syncthreads();

  const float bvo = 16.0f * beta_v[o];
  const float bao = beta_a[o];

  // block-uniform bases; per-idx offsets compile-time after unroll
  const float* pose_b = pose_t + ((size_t)((b * H_ + pi) * H_ + pj) << 8);
  const float* wt_l = wt + (l << 2);
  const int ci0 = wv * 2;

  // idx in [0,18): kk = idx>>1, ci = ci0 + (idx&1)
  // wt float-offset:   kk*4096 + ci*256
  // pose float-offset: (kk/3)*4096 + (kk%3)*256 + ci*16
#define WT_OFF(idx) ((((idx) >> 1) << 12) + ((ci0 + ((idx)&1)) << 8))
#define PB_OFF(idx) (((((idx) >> 1) / 3) << 12) + ((((idx) >> 1) % 3) << 8) + ((ci0 + ((idx)&1)) << 4))

  // ---- pass 1: packed fused mean+var partials; depth-2 wt prefetch ----
  float prr = 0.f;
  f2 pm01 = {0.f, 0.f}, pm23 = {0.f, 0.f}, pv01 = {0.f, 0.f}, pv23 = {0.f, 0.f};
  {
    float4 wbuf0 = *(const float4*)(wt_l + WT_OFF(0));
    float4 wbuf1 = *(const float4*)(wt_l + WT_OFF(1));
#pragma unroll
    for (int idx = 0; idx < 18; ++idx) {
      const float4 w4 = (idx & 1) ? wbuf1 : wbuf0;
      if (idx < 16) {
        if (idx & 1)
          wbuf1 = *(const float4*)(wt_l + WT_OFF(idx + 2));
        else
          wbuf0 = *(const float4*)(wt_l + WT_OFF(idx + 2));
      }
      const float* pb = pose_b + PB_OFF(idx);
      const float4 P0 = *(const float4*)(pb);
      const float4 P1 = *(const float4*)(pb + 4);
      const float4 P2 = *(const float4*)(pb + 8);
      const float4 P3 = *(const float4*)(pb + 12);
      f2 v01 = (f2){P0.x, P0.y} * w4.x;
      f2 v23 = (f2){P0.z, P0.w} * w4.x;
      v01 = __builtin_elementwise_fma((f2){P1.x, P1.y}, (f2){w4.y, w4.y}, v01);
      v23 = __builtin_elementwise_fma((f2){P1.z, P1.w}, (f2){w4.y, w4.y}, v23);
      v01 = __builtin_elementwise_fma((f2){P2.x, P2.y}, (f2){w4.z, w4.z}, v01);
      v23 = __builtin_elementwise_fma((f2){P2.z, P2.w}, (f2){w4.z, w4.z}, v23);
      v01 = __builtin_elementwise_fma((f2){P3.x, P3.y}, (f2){w4.w, w4.w}, v01);
      v23 = __builtin_elementwise_fma((f2){P3.z, P3.w}, (f2){w4.w, w4.w}, v23);
      const int k = ((idx >> 1) << 4) + ci0 + (idx & 1);
      const float rrk = (MODE == 0) ? rr_s[k] : rr_s[(k << 4) + o];
      prr += rrk;
      const f2 rr2 = {rrk, rrk};
      const f2 a01 = rr2 * v01, a23 = rr2 * v23;
      pm01 += a01;
      pm23 += a23;
      pv01 = __builtin_elementwise_fma(a01, v01, pv01);
      pv23 = __builtin_elementwise_fma(a23, v23, pv23);
    }
  }
  // ---- two-stage cross-wave combine ----
  partv[0][tid] = pm01; partv[1][tid] = pm23;
  partv[2][tid] = pv01; partv[3][tid] = pv23;
  partr[tid] = prr;
  __syncthreads();
  if (tid < 320) {
    if (tid < 256) {
      const int st = tid >> 6, li = tid & 63;
      f2 acc = partv[st][li];
#pragma unroll
      for (int wvi = 1; wvi < 8; ++wvi) acc += partv[st][wvi * 64 + li];
      sfin[st][li] = acc;
    } else {
      const int li = tid & 63;
      float acc = partr[li];
#pragma unroll
      for (int wvi = 1; wvi < 8; ++wvi) acc += partr[wvi * 64 + li];
      sfr[li] = acc;
    }
  }
  __syncthreads();
  const f2 S01 = sfin[0][l], S23 = sfin[1][l];
  const f2 V01 = sfin[2][l], V23 = sfin[3][l];
  const float rsum = sfr[l] + EPS_;
  const float irs = 1.0f / rsum;
  const f2 irs2 = {irs, irs};
  const f2 m01 = S01 * irs2, m23 = S23 * irs2;
  const f2 zero2 = {0.f, 0.f}, eps2 = {EPS_, EPS_};
  const f2 va01 = __builtin_elementwise_max(V01 * irs2 - m01 * m01, zero2) + eps2;
  const f2 va23 = __builtin_elementwise_max(V23 * irs2 - m23 * m23, zero2) + eps2;
  float slv = __logf(va01.x) + __logf(va01.y) + __logf(va23.x) + __logf(va23.y);
  slv += __shfl_xor(slv, 1);
  slv += __shfl_xor(slv, 2);
  const float cost = (bvo + 0.5f * slv) * rsum;
  const float aj = 1.0f / (1.0f + __expf(-inv_temp * (bao - cost)));

  if (MODE == 2) {
    if (wv == 0) {
      float* ob = out + ((size_t)(pid * 16 + o) << 4) + r;
      ob[0] = m01.x; ob[4] = m01.y; ob[8] = m23.x; ob[12] = m23.y;
      if (r == 0) out[(size_t)B_ * P2_ * O_ * 16 + pid * 16 + o] = aj;
    }
    return;
  }

  // ---- pass 2: recompute votes (depth-2 prefetch), write z[k][o] ----
  const f2 iv01 = {1.0f / va01.x, 1.0f / va01.y};
  const f2 iv23 = {1.0f / va23.x, 1.0f / va23.y};
  const float Cz = __logf(aj + EPS_) - 0.5f * (slv + 16.0f * LOG2PI_);
  float* zo = zout + (size_t)pid * NV_ + o;
  {
    float4 wbuf0 = *(const float4*)(wt_l + WT_OFF(0));
    float4 wbuf1 = *(const float4*)(wt_l + WT_OFF(1));
#pragma unroll
    for (int idx = 0; idx < 18; ++idx) {
      const float4 w4 = (idx & 1) ? wbuf1 : wbuf0;
      if (idx < 16) {
        if (idx & 1)
          wbuf1 = *(const float4*)(wt_l + WT_OFF(idx + 2));
        else
          wbuf0 = *(const float4*)(wt_l + WT_OFF(idx + 2));
      }
      const float* pb = pose_b + PB_OFF(idx);
      const float4 P0 = *(const float4*)(pb);
      const float4 P1 = *(const float4*)(pb + 4);
      const float4 P2 = *(const float4*)(pb + 8);
      const float4 P3 = *(const float4*)(pb + 12);
      f2 v01 = (f2){P0.x, P0.y} * w4.x;
      f2 v23 = (f2){P0.z, P0.w} * w4.x;
      v01 = __builtin_elementwise_fma((f2){P1.x, P1.y}, (f2){w4.y, w4.y}, v01);
      v23 = __builtin_elementwise_fma((f2){P1.z, P1.w}, (f2){w4.y, w4.y}, v23);
      v01 = __builtin_elementwise_fma((f2){P2.x, P2.y}, (f2){w4.z, w4.z}, v01);
      v23 = __builtin_elementwise_fma((f2){P2.z, P2.w}, (f2){w4.z, w4.z}, v23);
      v01 = __builtin_elementwise_fma((f2){P3.x, P3.y}, (f2){w4.w, w4.w}, v01);
      v23 = __builtin_elementwise_fma((f2){P3.z, P3.w}, (f2){w4.w, w4.w}, v23);
      const f2 d01 = v01 - m01, d23 = v23 - m23;
      const f2 q2 = __builtin_elementwise_fma(d01 * d01, iv01, (d23 * d23) * iv23);
      float q = q2.x + q2.y;
      q += __shfl_xor(q, 1);
      q += __shfl_xor(q, 2);
      const int k = ((idx >> 1) << 4) + ci0 + (idx & 1);
      if (r == 0) zo[k << 4] = Cz - 0.5f * q;  // 16 lanes -> one 64B line
    }
  }
#undef WT_OFF
#undef PB_OFF
}

// 4 threads per segment (b,h,w,ci); z cached in registers between max and sum.
__global__ __launch_bounds__(256) void seg_reduce(const float* __restrict__ z,
                                                  float* __restrict__ gmax,
                                                  float* __restrict__ gden) {
  const int tid = blockIdx.x * 256 + threadIdx.x;  // 0..131071
  const int part = tid & 3, ci = (tid >> 2) & 15, w2 = (tid >> 6) & 15;
  const int h = (tid >> 10) & 15, b = tid >> 14;
  float4 v[9];
  float m = -3.0e38f;
#pragma unroll
  for (int s = 0; s < 9; ++s) {
    const int ki = (s >= 6) ? 2 : (s >= 3) ? 1 : 0, kj = s - 3 * ki;
    const int pi = h - ki, pj = w2 - kj;
    if ((unsigned)pi < (unsigned)P_ && (unsigned)pj < (unsigned)P_) {
      v[s] = *(const float4*)(z + (size_t)(b * P2_ + pi * P_ + pj) * NV_ + s * 256 +
                              ci * 16 + part * 4);
    } else {
      v[s] = make_float4(-3.0e38f, -3.0e38f, -3.0e38f, -3.0e38f);
    }
    m = fmaxf(m, fmaxf(fmaxf(v[s].x, v[s].y), fmaxf(v[s].z, v[s].w)));
  }
  m = fmaxf(m, __shfl_xor(m, 1));
  m = fmaxf(m, __shfl_xor(m, 2));
  float s_ = 0.f;
#pragma unroll
  for (int s = 0; s < 9; ++s) {
    s_ += __expf(v[s].x - m) + __expf(v[s].y - m) + __expf(v[s].z - m) + __expf(v[s].w - m);
  }
  s_ += __shfl_xor(s_, 1);
  s_ += __shfl_xor(s_, 2);
  if (part == 0) {
    gmax[tid >> 2] = m;
    gden[tid >> 2] = s_;
  }
}
}  // namespace

extern "C" void kernel_launch(void* const* d_in, const int* in_sizes, int n_in,
                              void* d_out, int out_size, void* d_ws, size_t ws_size,
                              hipStream_t stream) {
  const float* pose = (const float*)d_in[0];
  const float* act = (const float*)d_in[1];
  const float* w = (const float*)d_in[2];
  const float* ba = (const float*)d_in[3];
  const float* bv = (const float*)d_in[4];
  float* out = (float*)d_out;

  float* z = (float*)d_ws;                  // 3,612,672 floats, layout [pid][k][o]
  float* gm = z + (size_t)B_ * P2_ * NV_;   // 32,768
  float* gd = gm + B_ * H_ * H_ * CI_;      // 32,768
  float* wt = gd + B_ * H_ * H_ * CI_;      // 36,864
  float* pt = wt + 36864;                   // 524,288 (pose transposed)

  const int NB = B_ * P2_;  // 1568 blocks, one per patch
  transpose_all<<<2192, 256, 0, stream>>>(pose, pt, w, wt);
  caps_main<0><<<NB, 512, 0, stream>>>(pt, act, wt, ba, bv, z, gm, gd, z, out);
  seg_reduce<<<512, 256, 0, stream>>>(z, gm, gd);
  caps_main<1><<<NB, 512, 0, stream>>>(pt, act, wt, ba, bv, z, gm, gd, z, out);
  seg_reduce<<<512, 256, 0, stream>>>(z, gm, gd);
  caps_main<2><<<NB, 512, 0, stream>>>(pt, act, wt, ba, bv, z, gm, gd, z, out);
}